// Round 1
// baseline (217.535 us; speedup 1.0000x reference)
//
#include <hip/hip_runtime.h>

#define HD 1024
#define ID 4096
#define NR 8192

typedef float f32x4 __attribute__((ext_vector_type(4)));
typedef __bf16 bf16x8 __attribute__((ext_vector_type(8)));

__device__ inline ushort f2bf(float f) {
    union { float f; unsigned u; } v; v.f = f;
    unsigned u = v.u;
    unsigned r = (u + 0x7fffu + ((u >> 16) & 1u)) >> 16;  // RNE
    return (ushort)r;
}

__device__ inline float wave_sum(float v) {
#pragma unroll
    for (int o = 32; o > 0; o >>= 1) v += __shfl_xor(v, o, 64);
    return v;
}

// ---------------- Kernel 1: LayerNorm + l2-normalize -> Q bf16 ----------------
__global__ __launch_bounds__(256) void ln_qnorm_kernel(
    const float* __restrict__ x, const float* __restrict__ w,
    const float* __restrict__ b, ushort* __restrict__ Q) {
    __shared__ float red[2][4];
    __shared__ float red2[4];
    const int row = blockIdx.x, t = threadIdx.x;
    const int lane = t & 63, wid = t >> 6;
    const float4 v = reinterpret_cast<const float4*>(x + (size_t)row * HD)[t];
    float s  = v.x + v.y + v.z + v.w;
    float ss = v.x*v.x + v.y*v.y + v.z*v.z + v.w*v.w;
    s = wave_sum(s); ss = wave_sum(ss);
    if (lane == 0) { red[0][wid] = s; red[1][wid] = ss; }
    __syncthreads();
    float st  = red[0][0] + red[0][1] + red[0][2] + red[0][3];
    float sst = red[1][0] + red[1][1] + red[1][2] + red[1][3];
    float mu   = st * (1.0f / HD);
    float var  = sst * (1.0f / HD) - mu * mu;
    float rstd = rsqrtf(var + 1e-12f);
    const float4 wv = reinterpret_cast<const float4*>(w)[t];
    const float4 bv = reinterpret_cast<const float4*>(b)[t];
    float y0 = (v.x - mu) * rstd * wv.x + bv.x;
    float y1 = (v.y - mu) * rstd * wv.y + bv.y;
    float y2 = (v.z - mu) * rstd * wv.z + bv.z;
    float y3 = (v.w - mu) * rstd * wv.w + bv.w;
    float n2 = wave_sum(y0*y0 + y1*y1 + y2*y2 + y3*y3);
    if (lane == 0) red2[wid] = n2;
    __syncthreads();
    float nt = red2[0] + red2[1] + red2[2] + red2[3];
    float sc = 1.0f / fmaxf(sqrtf(nt), 1e-12f);
    ushort4 o;
    o.x = f2bf(y0 * sc); o.y = f2bf(y1 * sc);
    o.z = f2bf(y2 * sc); o.w = f2bf(y3 * sc);
    reinterpret_cast<ushort4*>(Q + (size_t)row * HD)[t] = o;
}

// ---------------- Kernel 2: l2-normalize k_weight rows -> Kn bf16 ----------------
__global__ __launch_bounds__(256) void knorm_kernel(
    const float* __restrict__ kw, ushort* __restrict__ Kn) {
    __shared__ float red2[4];
    const int row = blockIdx.x, t = threadIdx.x;
    const int lane = t & 63, wid = t >> 6;
    const float4 v = reinterpret_cast<const float4*>(kw + (size_t)row * HD)[t];
    float n2 = wave_sum(v.x*v.x + v.y*v.y + v.z*v.z + v.w*v.w);
    if (lane == 0) red2[wid] = n2;
    __syncthreads();
    float nt = red2[0] + red2[1] + red2[2] + red2[3];
    float sc = 1.0f / fmaxf(sqrtf(nt), 1e-12f);
    ushort4 o;
    o.x = f2bf(v.x * sc); o.y = f2bf(v.y * sc);
    o.z = f2bf(v.z * sc); o.w = f2bf(v.w * sc);
    reinterpret_cast<ushort4*>(Kn + (size_t)row * HD)[t] = o;
}

// ---------------- Kernel 3: transpose+cast q_weight [I][H] -> VT bf16 [H][I] ----------------
__global__ __launch_bounds__(256) void tcvt_kernel(
    const float* __restrict__ V, ushort* __restrict__ VT) {
    __shared__ float tile[64][65];
    const int t = threadIdx.x;
    const int bi = blockIdx.x * 64, bh = blockIdx.y * 64;
    const int r0 = t >> 4, c0 = (t & 15) << 2;
#pragma unroll
    for (int rr = 0; rr < 64; rr += 16) {
        float4 val = *reinterpret_cast<const float4*>(
            &V[(size_t)(bi + rr + r0) * HD + bh + c0]);
        tile[rr + r0][c0 + 0] = val.x; tile[rr + r0][c0 + 1] = val.y;
        tile[rr + r0][c0 + 2] = val.z; tile[rr + r0][c0 + 3] = val.w;
    }
    __syncthreads();
#pragma unroll
    for (int rr = 0; rr < 64; rr += 16) {
        ushort4 o;
        o.x = f2bf(tile[c0 + 0][rr + r0]);
        o.y = f2bf(tile[c0 + 1][rr + r0]);
        o.z = f2bf(tile[c0 + 2][rr + r0]);
        o.w = f2bf(tile[c0 + 3][rr + r0]);
        *reinterpret_cast<ushort4*>(&VT[(size_t)(bh + rr + r0) * ID + bi + c0]) = o;
    }
}

// ---------------- GEMM (NT): C[m,n] = sum_k A[m,k]*B[n,k], bf16 in, f32 acc ----------------
// ACT=1: YOSO activation epilogue, bf16 out.  ACT=0: f32 out.
template <int ACT>
__global__ __launch_bounds__(256, 2) void gemm_bt_kernel(
    const ushort* __restrict__ A, const ushort* __restrict__ B,
    void* __restrict__ Cv, int M, int N, int K) {
    __shared__ ushort la[128 * 64] __attribute__((aligned(16)));
    __shared__ ushort lb[128 * 64] __attribute__((aligned(16)));
    const int tid = threadIdx.x;
    const int w = tid >> 6, lane = tid & 63;
    const int brow = blockIdx.x * 128;
    const int bcol = blockIdx.y * 128;
    const int wr = (w >> 1) * 64;  // wave row offset in tile
    const int wc = (w & 1) * 64;   // wave col offset in tile
    f32x4 acc[4][4] = {};
    const int srow = lane >> 3;          // 0..7 row within 8-row stripe
    const int scol = (lane & 7) << 3;    // 0..56 element offset

    for (int k0 = 0; k0 < K; k0 += 64) {
#pragma unroll
        for (int it = 0; it < 4; ++it) {
            const int rb = w * 32 + it * 8;
            const ushort* ga = A + (size_t)(brow + rb + srow) * K + k0 + scol;
            const ushort* gb = B + (size_t)(bcol + rb + srow) * K + k0 + scol;
            __builtin_amdgcn_global_load_lds(
                (const __attribute__((address_space(1))) void*)ga,
                (__attribute__((address_space(3))) void*)&la[rb * 64], 16, 0, 0);
            __builtin_amdgcn_global_load_lds(
                (const __attribute__((address_space(1))) void*)gb,
                (__attribute__((address_space(3))) void*)&lb[rb * 64], 16, 0, 0);
        }
        __syncthreads();
#pragma unroll
        for (int ks = 0; ks < 2; ++ks) {
            bf16x8 af[4], bfr[4];
            const int col = ks * 32 + (lane >> 4) * 8;
#pragma unroll
            for (int m = 0; m < 4; ++m)
                af[m] = *reinterpret_cast<const bf16x8*>(
                    &la[(wr + m * 16 + (lane & 15)) * 64 + col]);
#pragma unroll
            for (int n = 0; n < 4; ++n)
                bfr[n] = *reinterpret_cast<const bf16x8*>(
                    &lb[(wc + n * 16 + (lane & 15)) * 64 + col]);
#pragma unroll
            for (int m = 0; m < 4; ++m)
#pragma unroll
                for (int n = 0; n < 4; ++n)
                    acc[m][n] = __builtin_amdgcn_mfma_f32_16x16x32_bf16(
                        af[m], bfr[n], acc[m][n], 0, 0, 0);
        }
        __syncthreads();
    }
    // Epilogue. C frag mapping: col = lane&15, row = (lane>>4)*4 + r
    const int crow0 = brow + wr + ((lane >> 4) << 2);
    const int ccol0 = bcol + wc + (lane & 15);
#pragma unroll
    for (int m = 0; m < 4; ++m) {
#pragma unroll
        for (int n = 0; n < 4; ++n) {
#pragma unroll
            for (int r = 0; r < 4; ++r) {
                const int row = crow0 + m * 16 + r;
                const int col = ccol0 + n * 16;
                float v = acc[m][n][r];
                if (ACT) {
                    float s = fminf(fmaxf(v, -1.0f + 1e-6f), 1.0f - 1e-6f);
                    float tt = 1.0f - acosf(s) * 0.3183098861837907f;  // 1/pi
                    float t2 = tt * tt, t4 = t2 * t2, t8 = t4 * t4;
                    ((ushort*)Cv)[(size_t)row * N + col] = f2bf(t8 * tt);
                } else {
                    ((float*)Cv)[(size_t)row * N + col] = v;
                }
            }
        }
    }
}

// ---------------- Kernel 6: in-place row l2-normalize + bias ----------------
__global__ __launch_bounds__(256) void outnorm_kernel(
    float* __restrict__ X, const float* __restrict__ bias) {
    __shared__ float red2[4];
    const int row = blockIdx.x, t = threadIdx.x;
    const int lane = t & 63, wid = t >> 6;
    float4 v = reinterpret_cast<float4*>(X + (size_t)row * HD)[t];
    float n2 = wave_sum(v.x*v.x + v.y*v.y + v.z*v.z + v.w*v.w);
    if (lane == 0) red2[wid] = n2;
    __syncthreads();
    float nt = red2[0] + red2[1] + red2[2] + red2[3];
    float sc = 1.0f / fmaxf(sqrtf(nt), 1e-12f);
    const float4 bv = reinterpret_cast<const float4*>(bias)[t];
    float4 o;
    o.x = v.x * sc + bv.x; o.y = v.y * sc + bv.y;
    o.z = v.z * sc + bv.z; o.w = v.w * sc + bv.w;
    reinterpret_cast<float4*>(X + (size_t)row * HD)[t] = o;
}

extern "C" void kernel_launch(void* const* d_in, const int* in_sizes, int n_in,
                              void* d_out, int out_size, void* d_ws, size_t ws_size,
                              hipStream_t stream) {
    const float* hs   = (const float*)d_in[0];  // hidden_states [4,2048,1024]
    const float* lnw  = (const float*)d_in[1];  // ln_weight [1024]
    const float* lnb  = (const float*)d_in[2];  // ln_bias [1024]
    const float* kw   = (const float*)d_in[3];  // k_weight [4096,1024]
    const float* qw   = (const float*)d_in[4];  // q_weight [4096,1024]
    const float* bias = (const float*)d_in[5];  // bias [1024]
    float* out = (float*)d_out;

    char* ws = (char*)d_ws;
    ushort* Q    = (ushort*)(ws);                                  // 16 MiB
    ushort* Kn   = (ushort*)(ws + (size_t)16777216);               //  8 MiB
    ushort* VT   = (ushort*)(ws + (size_t)16777216 + 8388608);     //  8 MiB
    ushort* Bmat = (ushort*)(ws + (size_t)16777216 + 2 * 8388608); // 64 MiB

    ln_qnorm_kernel<<<NR, 256, 0, stream>>>(hs, lnw, lnb, Q);
    knorm_kernel<<<ID, 256, 0, stream>>>(kw, Kn);
    tcvt_kernel<<<dim3(ID / 64, HD / 64), 256, 0, stream>>>(qw, VT);
    gemm_bt_kernel<1><<<dim3(NR / 128, ID / 128), 256, 0, stream>>>(
        Q, Kn, (void*)Bmat, NR, ID, HD);
    gemm_bt_kernel<0><<<dim3(NR / 128, HD / 128), 256, 0, stream>>>(
        Bmat, VT, (void*)out, NR, HD, ID);
    outnorm_kernel<<<NR, 256, 0, stream>>>(out, bias);
}

// Round 2
// 209.877 us; speedup vs baseline: 1.0365x; 1.0365x over previous
//
#include <hip/hip_runtime.h>

#define HD 1024
#define ID 4096
#define NR 8192

typedef float f32x4 __attribute__((ext_vector_type(4)));
typedef __bf16 bf16x8 __attribute__((ext_vector_type(8)));

__device__ inline ushort f2bf(float f) {
    union { float f; unsigned u; } v; v.f = f;
    unsigned u = v.u;
    unsigned r = (u + 0x7fffu + ((u >> 16) & 1u)) >> 16;  // RNE
    return (ushort)r;
}

__device__ inline float wave_sum(float v) {
#pragma unroll
    for (int o = 32; o > 0; o >>= 1) v += __shfl_xor(v, o, 64);
    return v;
}

template <int N> __device__ __forceinline__ void vmw() {
    static_assert(N == 0 || N == 2 || N == 3 || N == 4, "vmcnt");
    if constexpr (N == 0) asm volatile("s_waitcnt vmcnt(0)" ::: "memory");
    else if constexpr (N == 2) asm volatile("s_waitcnt vmcnt(2)" ::: "memory");
    else if constexpr (N == 3) asm volatile("s_waitcnt vmcnt(3)" ::: "memory");
    else asm volatile("s_waitcnt vmcnt(4)" ::: "memory");
}
__device__ __forceinline__ void barrier_() {
    __builtin_amdgcn_sched_barrier(0);
    __builtin_amdgcn_s_barrier();
    __builtin_amdgcn_sched_barrier(0);
}
__device__ __forceinline__ void lgk0_() {
    asm volatile("s_waitcnt lgkmcnt(0)" ::: "memory");
    __builtin_amdgcn_sched_barrier(0);
}

// ---- 8-phase GEMM helpers (MH/NH compile-time -> no scratch, rule 20) ----
template <int NW, int MH>
__device__ __forceinline__ void load_a(const char* lds, bf16x8 (&areg)[4][2],
                                       int db, int wm, int l) {
#pragma unroll
    for (int m = 0; m < 4; ++m)
#pragma unroll
        for (int ks = 0; ks < 2; ++ks) {
            int s = wm * 64 + m * 16 + (l & 15);
            areg[m][ks] = *(const bf16x8*)(lds + db * 32768 + MH * 16384 + s * 128 +
                                           ((ks * 64 + ((l >> 4) << 4)) ^ ((l & 7) << 4)));
        }
}
template <int NW, int NH>
__device__ __forceinline__ void load_b(const char* lds, bf16x8 (&breg)[2][NW][2],
                                       int db, int wn, int l) {
#pragma unroll
    for (int n = 0; n < NW; ++n)
#pragma unroll
        for (int ks = 0; ks < 2; ++ks) {
            int s = wn * (16 * NW) + n * 16 + (l & 15);
            breg[NH][n][ks] = *(const bf16x8*)(lds + 65536 + db * (NW * 16384) +
                                               NH * (NW * 8192) + s * 128 +
                                               ((ks * 64 + ((l >> 4) << 4)) ^ ((l & 7) << 4)));
        }
}
template <int NW, int MH, int NH>
__device__ __forceinline__ void mma_ph(f32x4 (&acc)[8][2 * NW],
                                       const bf16x8 (&areg)[4][2],
                                       const bf16x8 (&breg)[2][NW][2]) {
#pragma unroll
    for (int m = 0; m < 4; ++m)
#pragma unroll
        for (int n = 0; n < NW; ++n)
#pragma unroll
            for (int ks = 0; ks < 2; ++ks)
                acc[MH * 4 + m][NH * NW + n] = __builtin_amdgcn_mfma_f32_16x16x32_bf16(
                    areg[m][ks], breg[NH][n][ks], acc[MH * 4 + m][NH * NW + n], 0, 0, 0);
}

// NT GEMM, 256 x (128*NW) tile, BK=64, 8 waves, 8-phase counted-vmcnt schedule.
// NW=2: BN=256 (ACT=1 YOSO epilogue, bf16 out). NW=1: BN=128 (ACT=0, f32 out).
template <int NW, int ACT>
__global__ __launch_bounds__(512, 2) void gemm8p_kernel(
    const ushort* __restrict__ Ap, const ushort* __restrict__ Bp,
    void* __restrict__ Cv, int N, int K, int nt) {
    __shared__ char lds[131072] __attribute__((aligned(16)));
    const int tid = threadIdx.x;
    const int w = tid >> 6, l = tid & 63;
    const int wm = w >> 2, wn = w & 3;
    const int bid = blockIdx.x;
    const int swz = (bid & 7) * ((int)gridDim.x >> 3) + (bid >> 3);  // XCD swizzle (nwg%8==0)
    const int brow = (swz & 31) * 256;
    const int bcol = (swz >> 5) * (128 * NW);
    const int colsw = ((l & 7) ^ (l >> 3)) << 4;  // pre-swizzled global src col (T2 inverse)

    f32x4 acc[8][2 * NW] = {};
    bf16x8 areg[4][2];
    bf16x8 breg[2][NW][2];

    // stage unit: A-half (by consumption order mh) -> 128 slot-rows, 2 loads/thread
    auto sA = [&](int t, int mh) {
#pragma unroll
        for (int i = 0; i < 2; ++i) {
            int s = (w * 2 + i) * 8 + (l >> 3);
            int r = ((s >> 6) << 7) + mh * 64 + (s & 63);  // slot -> global row
            const char* src = (const char*)Ap + (((size_t)(brow + r) * K + t * 64) << 1) + colsw;
            __builtin_amdgcn_global_load_lds(
                (const __attribute__((address_space(1))) void*)src,
                (__attribute__((address_space(3))) void*)&lds[(t & 1) * 32768 + mh * 16384 +
                                                              (w * 2 + i) * 1024],
                16, 0, 0);
        }
    };
    // stage unit: B rows for quadrant nh (permuted-contiguous), NW loads/thread
    auto sB = [&](int t, int nh) {
#pragma unroll
        for (int i = 0; i < NW; ++i) {
            constexpr int SH = (NW == 2) ? 5 : 4;
            int s = (w * NW + i) * 8 + (l >> 3);
            int r = ((s >> SH) << (SH + 1)) + nh * (16 * NW) + (s & (16 * NW - 1));
            const char* src = (const char*)Bp + (((size_t)(bcol + r) * K + t * 64) << 1) + colsw;
            __builtin_amdgcn_global_load_lds(
                (const __attribute__((address_space(1))) void*)src,
                (__attribute__((address_space(3))) void*)&lds[65536 + (t & 1) * (NW * 16384) +
                                                              nh * (NW * 8192) + (w * NW + i) * 1024],
                16, 0, 0);
        }
    };

    // prologue: stage tile 0 (u1=A.mh0, u2=B.nh0, u3=B.nh1, u4=A.mh1); land u1,u2
    sA(0, 0); sB(0, 0); sB(0, 1); sA(0, 1);
    vmw<NW + 2>();
    barrier_();

    for (int t = 0; t < nt; ++t) {
        const int db = t & 1;
        const bool more = (t + 1 < nt);
        // ---- ph1: quadrant (mh0,nh0); stage (t+1).A.mh0 ----
        load_a<NW, 0>(lds, areg, db, wm, l);
        load_b<NW, 0>(lds, breg, db, wn, l);
        if (more) sA(t + 1, 0);
        barrier_(); lgk0_();
        __builtin_amdgcn_s_setprio(1);
        mma_ph<NW, 0, 0>(acc, areg, breg);
        __builtin_amdgcn_s_setprio(0);
        __builtin_amdgcn_sched_barrier(0);
        if (more) vmw<4>(); else vmw<2>();   // lands t.u3 (B.nh1)
        barrier_();
        // ---- ph2: (mh0,nh1); stage (t+1).B.nh0 ----
        load_b<NW, 1>(lds, breg, db, wn, l);
        if (more) sB(t + 1, 0);
        barrier_(); lgk0_();
        __builtin_amdgcn_s_setprio(1);
        mma_ph<NW, 0, 1>(acc, areg, breg);
        __builtin_amdgcn_s_setprio(0);
        __builtin_amdgcn_sched_barrier(0);
        if (more) vmw<NW + 2>(); else vmw<0>();  // lands t.u4 (A.mh1)
        barrier_();
        // ---- ph3: (mh1,nh1); stage (t+1).B.nh1 ----
        load_a<NW, 1>(lds, areg, db, wm, l);
        if (more) sB(t + 1, 1);
        barrier_(); lgk0_();
        __builtin_amdgcn_s_setprio(1);
        mma_ph<NW, 1, 1>(acc, areg, breg);
        __builtin_amdgcn_s_setprio(0);
        barrier_();
        // ---- ph4: (mh1,nh0) — B.nh0 frags still in regs; stage (t+1).A.mh1 ----
        if (more) sA(t + 1, 1);
        barrier_();
        __builtin_amdgcn_s_setprio(1);
        mma_ph<NW, 1, 0>(acc, areg, breg);
        __builtin_amdgcn_s_setprio(0);
        __builtin_amdgcn_sched_barrier(0);
        if (more) vmw<NW + 2>();             // lands (t+1).u1,u2
        barrier_();
    }

    // ---- epilogue: per-wave 16 KiB LDS slice -> coalesced 16B stores ----
    char* wsl = lds + w * 16384;
    constexpr int E = ACT ? 2 : 4;
#pragma unroll
    for (int m = 0; m < 8; ++m)
#pragma unroll
        for (int n = 0; n < 2 * NW; ++n)
#pragma unroll
            for (int r = 0; r < 4; ++r) {
                int row = m * 16 + ((l >> 4) << 2) + r;
                int colb = (n * 16 + (l & 15)) * E;
                float v = acc[m][n][r];
                if (ACT) {
                    float s = fminf(fmaxf(v, -1.0f + 1e-6f), 1.0f - 1e-6f);
                    float tt = 1.0f - acosf(s) * 0.3183098861837907f;
                    float t2 = tt * tt, t4 = t2 * t2, t8 = t4 * t4;
                    *(ushort*)(wsl + row * 128 + (colb ^ ((row & 7) << 4))) = f2bf(t8 * tt);
                } else {
                    *(float*)(wsl + row * 128 + (colb ^ ((row & 7) << 4))) = v;
                }
            }
    asm volatile("s_waitcnt lgkmcnt(0)" ::: "memory");  // wave-local slice: no barrier needed
#pragma unroll
    for (int it = 0; it < 16; ++it) {
        int row = it * 8 + (l >> 3);
        int cb = (l & 7) * 16;
        uint4 d = *(const uint4*)(wsl + row * 128 + (cb ^ ((row & 7) << 4)));
        int grow = brow + wm * 128 + row;
        if (ACT) {
            size_t off = ((size_t)grow * N + (bcol + wn * 64)) * 2 + cb;
            *(uint4*)((char*)Cv + off) = d;
        } else {
            size_t off = ((size_t)grow * N + (bcol + wn * 32)) * 4 + cb;
            *(uint4*)((char*)Cv + off) = d;
        }
    }
}

// ---------------- Kernel 1: LayerNorm + l2-normalize -> Q bf16 ----------------
__global__ __launch_bounds__(256) void ln_qnorm_kernel(
    const float* __restrict__ x, const float* __restrict__ w,
    const float* __restrict__ b, ushort* __restrict__ Q) {
    __shared__ float red[2][4];
    __shared__ float red2[4];
    const int row = blockIdx.x, t = threadIdx.x;
    const int lane = t & 63, wid = t >> 6;
    const float4 v = reinterpret_cast<const float4*>(x + (size_t)row * HD)[t];
    float s  = v.x + v.y + v.z + v.w;
    float ss = v.x*v.x + v.y*v.y + v.z*v.z + v.w*v.w;
    s = wave_sum(s); ss = wave_sum(ss);
    if (lane == 0) { red[0][wid] = s; red[1][wid] = ss; }
    __syncthreads();
    float st  = red[0][0] + red[0][1] + red[0][2] + red[0][3];
    float sst = red[1][0] + red[1][1] + red[1][2] + red[1][3];
    float mu   = st * (1.0f / HD);
    float var  = sst * (1.0f / HD) - mu * mu;
    float rstd = rsqrtf(var + 1e-12f);
    const float4 wv = reinterpret_cast<const float4*>(w)[t];
    const float4 bv = reinterpret_cast<const float4*>(b)[t];
    float y0 = (v.x - mu) * rstd * wv.x + bv.x;
    float y1 = (v.y - mu) * rstd * wv.y + bv.y;
    float y2 = (v.z - mu) * rstd * wv.z + bv.z;
    float y3 = (v.w - mu) * rstd * wv.w + bv.w;
    float n2 = wave_sum(y0*y0 + y1*y1 + y2*y2 + y3*y3);
    if (lane == 0) red2[wid] = n2;
    __syncthreads();
    float nt = red2[0] + red2[1] + red2[2] + red2[3];
    float sc = 1.0f / fmaxf(sqrtf(nt), 1e-12f);
    ushort4 o;
    o.x = f2bf(y0 * sc); o.y = f2bf(y1 * sc);
    o.z = f2bf(y2 * sc); o.w = f2bf(y3 * sc);
    reinterpret_cast<ushort4*>(Q + (size_t)row * HD)[t] = o;
}

// ---------------- Kernel 2: l2-normalize k_weight rows -> Kn bf16 ----------------
__global__ __launch_bounds__(256) void knorm_kernel(
    const float* __restrict__ kw, ushort* __restrict__ Kn) {
    __shared__ float red2[4];
    const int row = blockIdx.x, t = threadIdx.x;
    const int lane = t & 63, wid = t >> 6;
    const float4 v = reinterpret_cast<const float4*>(kw + (size_t)row * HD)[t];
    float n2 = wave_sum(v.x*v.x + v.y*v.y + v.z*v.z + v.w*v.w);
    if (lane == 0) red2[wid] = n2;
    __syncthreads();
    float nt = red2[0] + red2[1] + red2[2] + red2[3];
    float sc = 1.0f / fmaxf(sqrtf(nt), 1e-12f);
    ushort4 o;
    o.x = f2bf(v.x * sc); o.y = f2bf(v.y * sc);
    o.z = f2bf(v.z * sc); o.w = f2bf(v.w * sc);
    reinterpret_cast<ushort4*>(Kn + (size_t)row * HD)[t] = o;
}

// ---------------- Kernel 3: transpose+cast q_weight [I][H] -> VT bf16 [H][I] ----------------
__global__ __launch_bounds__(256) void tcvt_kernel(
    const float* __restrict__ V, ushort* __restrict__ VT) {
    __shared__ float tile[64][65];
    const int t = threadIdx.x;
    const int bi = blockIdx.x * 64, bh = blockIdx.y * 64;
    const int r0 = t >> 4, c0 = (t & 15) << 2;
#pragma unroll
    for (int rr = 0; rr < 64; rr += 16) {
        float4 val = *reinterpret_cast<const float4*>(
            &V[(size_t)(bi + rr + r0) * HD + bh + c0]);
        tile[rr + r0][c0 + 0] = val.x; tile[rr + r0][c0 + 1] = val.y;
        tile[rr + r0][c0 + 2] = val.z; tile[rr + r0][c0 + 3] = val.w;
    }
    __syncthreads();
#pragma unroll
    for (int rr = 0; rr < 64; rr += 16) {
        ushort4 o;
        o.x = f2bf(tile[c0 + 0][rr + r0]);
        o.y = f2bf(tile[c0 + 1][rr + r0]);
        o.z = f2bf(tile[c0 + 2][rr + r0]);
        o.w = f2bf(tile[c0 + 3][rr + r0]);
        *reinterpret_cast<ushort4*>(&VT[(size_t)(bh + rr + r0) * ID + bi + c0]) = o;
    }
}

// ---------------- Kernel 6: in-place row l2-normalize + bias ----------------
__global__ __launch_bounds__(256) void outnorm_kernel(
    float* __restrict__ X, const float* __restrict__ bias) {
    __shared__ float red2[4];
    const int row = blockIdx.x, t = threadIdx.x;
    const int lane = t & 63, wid = t >> 6;
    float4 v = reinterpret_cast<float4*>(X + (size_t)row * HD)[t];
    float n2 = wave_sum(v.x*v.x + v.y*v.y + v.z*v.z + v.w*v.w);
    if (lane == 0) red2[wid] = n2;
    __syncthreads();
    float nt = red2[0] + red2[1] + red2[2] + red2[3];
    float sc = 1.0f / fmaxf(sqrtf(nt), 1e-12f);
    const float4 bv = reinterpret_cast<const float4*>(bias)[t];
    float4 o;
    o.x = v.x * sc + bv.x; o.y = v.y * sc + bv.y;
    o.z = v.z * sc + bv.z; o.w = v.w * sc + bv.w;
    reinterpret_cast<float4*>(X + (size_t)row * HD)[t] = o;
}

extern "C" void kernel_launch(void* const* d_in, const int* in_sizes, int n_in,
                              void* d_out, int out_size, void* d_ws, size_t ws_size,
                              hipStream_t stream) {
    const float* hs   = (const float*)d_in[0];  // hidden_states [4,2048,1024]
    const float* lnw  = (const float*)d_in[1];  // ln_weight [1024]
    const float* lnb  = (const float*)d_in[2];  // ln_bias [1024]
    const float* kw   = (const float*)d_in[3];  // k_weight [4096,1024]
    const float* qw   = (const float*)d_in[4];  // q_weight [4096,1024]
    const float* bias = (const float*)d_in[5];  // bias [1024]
    float* out = (float*)d_out;

    char* ws = (char*)d_ws;
    ushort* Q    = (ushort*)(ws);                                  // 16 MiB
    ushort* Kn   = (ushort*)(ws + (size_t)16777216);               //  8 MiB
    ushort* VT   = (ushort*)(ws + (size_t)16777216 + 8388608);     //  8 MiB
    ushort* Bmat = (ushort*)(ws + (size_t)16777216 + 2 * 8388608); // 64 MiB

    ln_qnorm_kernel<<<NR, 256, 0, stream>>>(hs, lnw, lnb, Q);
    knorm_kernel<<<ID, 256, 0, stream>>>(kw, Kn);
    tcvt_kernel<<<dim3(ID / 64, HD / 64), 256, 0, stream>>>(qw, VT);
    // GEMM1: [8192,1024] x [4096,1024]^T -> act -> Bmat bf16 [8192,4096]
    gemm8p_kernel<2, 1><<<(NR / 256) * (ID / 256), 512, 0, stream>>>(
        Q, Kn, (void*)Bmat, ID, HD, HD / 64);
    // GEMM2: [8192,4096] x [1024,4096]^T -> out f32 [8192,1024]
    gemm8p_kernel<1, 0><<<(NR / 256) * (HD / 128), 512, 0, stream>>>(
        Bmat, VT, (void*)out, HD, ID, ID / 64);
    outnorm_kernel<<<NR, 256, 0, stream>>>(out, bias);
}